// Round 1
// baseline (63.493 us; speedup 1.0000x reference)
//
#include <hip/hip_runtime.h>

// MeshNN: u(x) = sum_j w_uu[j] * hat_j(x) + w_dd[0]*phi_0(x) + w_dd[1]*phi_L(x)
// Hats have compact support (c[j], c[j+2]) -- ReLU gives EXACT zeros outside,
// so only 2 interior hats + 2 boundary hats can be nonzero per point.
// Memory-bound: 2 MB in + 2 MB out.

#define TPf ((float)(1.0 - 1.0 / 150.0))
#define TMf ((float)(1.0 + 1.0 / 150.0))

__device__ __forceinline__ float hat_eval(float x, float xm, float xi, float xp) {
    // left  = relu(relu(xi - x) * (-1/(xi - xm)) + 1)
    // right = relu(relu(x - xi) * (-1/(xp - xi)) + 1)
    float l = fmaxf(fmaxf(xi - x, 0.0f) * (-1.0f / (xi - xm)) + 1.0f, 0.0f);
    float r = fmaxf(fmaxf(x - xi, 0.0f) * (-1.0f / (xp - xi)) + 1.0f, 0.0f);
    return l + r - 1.0f;
}

__global__ __launch_bounds__(256) void MeshNN_29042568855825_kernel(
    const float* __restrict__ X,   // (n,)
    const float* __restrict__ C,   // (258,)
    const float* __restrict__ Wu,  // (256,)
    const float* __restrict__ Wd,  // (2,)
    float* __restrict__ Out,       // (n,)
    int n)
{
    __shared__ float sc[258];
    __shared__ float sw[256];
    __shared__ float swd[2];
    const int tid = threadIdx.x;
    for (int j = tid; j < 258; j += 256) sc[j] = C[j];
    sw[tid] = Wu[tid];
    if (tid < 2) swd[tid] = Wd[tid];
    __syncthreads();

    // Boundary-hat constants (same for every point; transcribed from reference)
    const float c0 = sc[0], c1 = sc[1], cNm2 = sc[256], cNm1 = sc[257];
    const float xm0 = c0 - cNm1 / 100.0f;                       // c[0] - c[-1]/100
    const float xi0 = fmaxf(fminf(c0, TPf * c1), TMf * xm0);
    const float xpL = cNm1 * (float)(1.0 + 1.0 / 100.0);        // c[-1]*1.01
    const float xiL = fmaxf(fminf(cNm1, TPf * xpL), TMf * cNm2);
    const float inv_h = 257.0f / (cNm1 - c0);
    const float wd0 = swd[0], wd1 = swd[1];

    const int g = blockIdx.x * 256 + tid;       // float4 group index
    const int base = g * 4;
    if (base >= n) return;

    float xs[4];
    const bool full = (base + 3) < n;
    if (full) {
        float4 xv = ((const float4*)X)[g];
        xs[0] = xv.x; xs[1] = xv.y; xs[2] = xv.z; xs[3] = xv.w;
    } else {
        #pragma unroll
        for (int k = 0; k < 4; ++k) xs[k] = (base + k < n) ? X[base + k] : 0.0f;
    }

    float us[4];
    #pragma unroll
    for (int k = 0; k < 4; ++k) {
        const float x = xs[k];
        // locate interval i : sc[i] <= x < sc[i+1]
        int i = (int)((x - c0) * inv_h);
        i = min(max(i, 0), 256);
        while (i > 0 && x < sc[i]) --i;
        while (i < 256 && x >= sc[i + 1]) ++i;

        // boundary hats: exact zero away from edges, always evaluate (cheap)
        float u = wd0 * hat_eval(x, xm0, xi0, c1)
                + wd1 * hat_eval(x, cNm2, xiL, xpL);

        // interior hat j = i-1: support (c[i-1], c[i+1])
        if (i >= 1) {
            const float xm = sc[i - 1], xr = sc[i], xp = sc[i + 1];
            const float xic = fmaxf(fminf(xr, TPf * xp), TMf * xm);
            u += sw[i - 1] * hat_eval(x, xm, xic, xp);
        }
        // interior hat j = i: support (c[i], c[i+2])
        if (i <= 255) {
            const float xm = sc[i], xr = sc[i + 1], xp = sc[i + 2];
            const float xic = fmaxf(fminf(xr, TPf * xp), TMf * xm);
            u += sw[i] * hat_eval(x, xm, xic, xp);
        }
        us[k] = u;
    }

    if (full) {
        ((float4*)Out)[g] = make_float4(us[0], us[1], us[2], us[3]);
    } else {
        #pragma unroll
        for (int k = 0; k < 4; ++k)
            if (base + k < n) Out[base + k] = us[k];
    }
}

extern "C" void kernel_launch(void* const* d_in, const int* in_sizes, int n_in,
                              void* d_out, int out_size, void* d_ws, size_t ws_size,
                              hipStream_t stream) {
    const float* x  = (const float*)d_in[0];   // (500000,1) fp32
    const float* c  = (const float*)d_in[1];   // (258,)     fp32
    const float* wu = (const float*)d_in[2];   // (256,)     fp32
    const float* wd = (const float*)d_in[3];   // (2,)       fp32
    float* out = (float*)d_out;                // (500000,1) fp32

    const int n = in_sizes[0];
    const int ngroups = (n + 3) / 4;
    const int blocks = (ngroups + 255) / 256;
    MeshNN_29042568855825_kernel<<<blocks, 256, 0, stream>>>(x, c, wu, wd, out, n);
}

// Round 2
// 62.259 us; speedup vs baseline: 1.0198x; 1.0198x over previous
//
#include <hip/hip_runtime.h>

// MeshNN: u(x) = sum_j w_uu[j]*hat_j(x) + w_dd[0]*phi_0(x) + w_dd[1]*phi_L(x)
// Hats have compact support (c[j], c[j+2]): only 2 interior hats + 2 boundary
// hats are nonzero per point -> O(1) work/point. Memory: 2 MB in + 2 MB out.
//
// R2: 1 point/thread (1954 blocks, ~30 waves/CU for latency hiding) and all
// per-node clamped centers + reciprocals precomputed in LDS at stage time
// (replaces 8 fp32 divides/point with LDS reads; -1/d == -(1/d) exactly).

#define TPf ((float)(1.0 - 1.0 / 150.0))
#define TMf ((float)(1.0 + 1.0 / 150.0))

__device__ __forceinline__ float hat_rcp(float x, float xm, float xi, float xp,
                                         float rl, float rr) {
    // left  = relu(relu(xi - x) * (-1/(xi - xm)) + 1)   with rl = 1/(xi - xm)
    // right = relu(relu(x - xi) * (-1/(xp - xi)) + 1)   with rr = 1/(xp - xi)
    float l = fmaxf(fmaxf(xi - x, 0.0f) * (-rl) + 1.0f, 0.0f);
    float r = fmaxf(fmaxf(x - xi, 0.0f) * (-rr) + 1.0f, 0.0f);
    return l + r - 1.0f;
}

__global__ __launch_bounds__(256) void MeshNN_29042568855825_kernel(
    const float* __restrict__ X,   // (n,)
    const float* __restrict__ C,   // (258,)
    const float* __restrict__ Wu,  // (256,)
    const float* __restrict__ Wd,  // (2,)
    float* __restrict__ Out,       // (n,)
    int n)
{
    __shared__ float sc[258];   // node coordinates
    __shared__ float sxi[256];  // clamped center of interior hat j
    __shared__ float srl[256];  // 1/(xi - xm) for interior hat j
    __shared__ float srr[256];  // 1/(xp - xi) for interior hat j
    __shared__ float sw[256];   // w_uu
    __shared__ float sb[12];    // boundary consts: xm0,xi0,c1,rl0,rr0, cNm2,xiL,xpL,rlL,rrL, wd0,wd1

    const int tid = threadIdx.x;
    for (int j = tid; j < 258; j += 256) sc[j] = C[j];
    __syncthreads();

    {
        const int j = tid;  // interior hat j: xm=c[j], xi=c[j+1] clamped, xp=c[j+2]
        const float xm = sc[j], xr = sc[j + 1], xp = sc[j + 2];
        const float xic = fmaxf(fminf(xr, TPf * xp), TMf * xm);
        sxi[j] = xic;
        srl[j] = 1.0f / (xic - xm);
        srr[j] = 1.0f / (xp - xic);
        sw[j]  = Wu[j];
    }
    if (tid == 0) {
        const float c0 = sc[0], c1 = sc[1], cNm2 = sc[256], cNm1 = sc[257];
        const float xm0 = c0 - cNm1 / 100.0f;                 // c[0] - c[-1]/100
        const float xi0 = fmaxf(fminf(c0, TPf * c1), TMf * xm0);
        const float xpL = cNm1 * (float)(1.0 + 1.0 / 100.0);  // c[-1]*1.01
        const float xiL = fmaxf(fminf(cNm1, TPf * xpL), TMf * cNm2);
        sb[0] = xm0;  sb[1] = xi0;  sb[2] = c1;
        sb[3] = 1.0f / (xi0 - xm0); sb[4] = 1.0f / (c1 - xi0);
        sb[5] = cNm2; sb[6] = xiL;  sb[7] = xpL;
        sb[8] = 1.0f / (xiL - cNm2); sb[9] = 1.0f / (xpL - xiL);
        sb[10] = Wd[0]; sb[11] = Wd[1];
    }
    __syncthreads();

    const int idx = blockIdx.x * 256 + tid;
    if (idx >= n) return;

    const float c0 = sc[0];
    const float inv_h = 257.0f / (sc[257] - c0);
    const float x = X[idx];

    // locate interval i : sc[i] <= x < sc[i+1]
    int i = (int)((x - c0) * inv_h);
    i = min(max(i, 0), 256);
    while (i > 0 && x < sc[i]) --i;
    while (i < 256 && x >= sc[i + 1]) ++i;

    // boundary hats (exact zero away from edges, always cheap now)
    float u = sb[10] * hat_rcp(x, sb[0], sb[1], sb[2], sb[3], sb[4])
            + sb[11] * hat_rcp(x, sb[5], sb[6], sb[7], sb[8], sb[9]);

    // interior hat j = i-1: support (c[i-1], c[i+1])
    if (i >= 1) {
        const int j = i - 1;
        u += sw[j] * hat_rcp(x, sc[j], sxi[j], sc[j + 2], srl[j], srr[j]);
    }
    // interior hat j = i: support (c[i], c[i+2])
    if (i <= 255) {
        const int j = i;
        u += sw[j] * hat_rcp(x, sc[j], sxi[j], sc[j + 2], srl[j], srr[j]);
    }

    Out[idx] = u;
}

extern "C" void kernel_launch(void* const* d_in, const int* in_sizes, int n_in,
                              void* d_out, int out_size, void* d_ws, size_t ws_size,
                              hipStream_t stream) {
    const float* x  = (const float*)d_in[0];   // (500000,1) fp32
    const float* c  = (const float*)d_in[1];   // (258,)     fp32
    const float* wu = (const float*)d_in[2];   // (256,)     fp32
    const float* wd = (const float*)d_in[3];   // (2,)       fp32
    float* out = (float*)d_out;                // (500000,1) fp32

    const int n = in_sizes[0];
    const int blocks = (n + 255) / 256;
    MeshNN_29042568855825_kernel<<<blocks, 256, 0, stream>>>(x, c, wu, wd, out, n);
}